// Round 1
// baseline (261.885 us; speedup 1.0000x reference)
//
#include <hip/hip_runtime.h>
#include <hip/hip_bf16.h>
#include <cstdint>
#include <cstddef>

#define SEQ   2048
#define BATCH 2
#define NROWS 4096          // BATCH*SEQ
#define EMB   1024
#define NHEAD 16
#define HD    64

typedef __attribute__((ext_vector_type(8))) short bf16x8;
typedef __attribute__((ext_vector_type(4))) float f32x4;
typedef __hip_bfloat16 bf16_t;

// ---------------- cast f32 -> bf16 (vectorized) ----------------
__global__ __launch_bounds__(256) void cast_f32_to_bf16(const float* __restrict__ in,
                                                        bf16_t* __restrict__ out, int n4) {
  int i = blockIdx.x * 256 + threadIdx.x;
  if (i >= n4) return;
  float4 v = reinterpret_cast<const float4*>(in)[i];
  union { ushort4 u; bf16_t h[4]; } o;
  o.h[0] = __float2bfloat16(v.x);
  o.h[1] = __float2bfloat16(v.y);
  o.h[2] = __float2bfloat16(v.z);
  o.h[3] = __float2bfloat16(v.w);
  reinterpret_cast<ushort4*>(out)[i] = o.u;
}

// ---------------- 128x128 bf16 MFMA GEMM (m97 structure) ----------------
// Computes Y = A @ W^T  with A [M][1024] bf16 row-major, W [N][1024] bf16 row-major.
// MODE 0: write bf16 to Ob.  MODE 1: write f32 (acc + Res) to Of.
template <int MODE>
__device__ __forceinline__ void gemm128_body(const bf16_t* __restrict__ A,
                                             const bf16_t* __restrict__ W,
                                             bf16_t* __restrict__ Ob,
                                             float* __restrict__ Of,
                                             const float* __restrict__ Res) {
  __shared__ __align__(16) bf16_t As[128 * 32];
  __shared__ __align__(16) bf16_t Bs[128 * 32];
  const int tid = threadIdx.x;
  const int lane = tid & 63;
  const int wv = tid >> 6;
  const int wm = wv >> 1, wn = wv & 1;          // 2x2 waves, each owns 64x64
  const int brow = blockIdx.y * 128;
  const int bcol = blockIdx.x * 128;
  const int lr = lane & 15, lg = lane >> 4;

  f32x4 acc[4][4] = {};

  auto* As3 = (__attribute__((address_space(3))) char*)As;
  auto* Bs3 = (__attribute__((address_space(3))) char*)Bs;

  for (int k0 = 0; k0 < EMB; k0 += 32) {
    __syncthreads();  // previous tile's ds_reads done before overwrite
#pragma unroll
    for (int i = 0; i < 2; ++i) {
      const int chunk = i * 256 + tid;          // 0..511, 16B each = 8KB tile
      const int row = chunk >> 2;               // tile row 0..127
      const int kc = (chunk & 3) * 8;           // k element 0/8/16/24
      const bf16_t* ga = A + (size_t)(brow + row) * EMB + k0 + kc;
      const bf16_t* gb = W + (size_t)(bcol + row) * EMB + k0 + kc;
      __builtin_amdgcn_global_load_lds((const __attribute__((address_space(1))) void*)ga,
                                       (__attribute__((address_space(3))) void*)(As3 + chunk * 16),
                                       16, 0, 0);
      __builtin_amdgcn_global_load_lds((const __attribute__((address_space(1))) void*)gb,
                                       (__attribute__((address_space(3))) void*)(Bs3 + chunk * 16),
                                       16, 0, 0);
    }
    __syncthreads();  // compiler drains vmcnt(0) before barrier

    bf16x8 af[4], bfr[4];
#pragma unroll
    for (int m = 0; m < 4; ++m)
      af[m] = *reinterpret_cast<const bf16x8*>(&As[(wm * 64 + m * 16 + lr) * 32 + lg * 8]);
#pragma unroll
    for (int n = 0; n < 4; ++n)
      bfr[n] = *reinterpret_cast<const bf16x8*>(&Bs[(wn * 64 + n * 16 + lr) * 32 + lg * 8]);
#pragma unroll
    for (int m = 0; m < 4; ++m)
#pragma unroll
      for (int n = 0; n < 4; ++n)
        acc[m][n] = __builtin_amdgcn_mfma_f32_16x16x32_bf16(af[m], bfr[n], acc[m][n], 0, 0, 0);
  }

  const int r0 = brow + wm * 64;
  const int c0 = bcol + wn * 64;
#pragma unroll
  for (int m = 0; m < 4; ++m)
#pragma unroll
    for (int n = 0; n < 4; ++n)
#pragma unroll
      for (int r = 0; r < 4; ++r) {
        // C/D layout (m89-verified): col = lane&15, row = (lane>>4)*4 + reg
        const int row = r0 + m * 16 + lg * 4 + r;
        const int col = c0 + n * 16 + lr;
        const size_t idx = (size_t)row * EMB + col;
        if (MODE == 0) {
          Ob[idx] = __float2bfloat16(acc[m][n][r]);
        } else {
          Of[idx] = acc[m][n][r] + Res[idx];
        }
      }
}

__global__ __launch_bounds__(256) void gemm_qkv(const bf16_t* __restrict__ X,
                                                const bf16_t* __restrict__ Wq,
                                                const bf16_t* __restrict__ Wk,
                                                const bf16_t* __restrict__ Wv,
                                                bf16_t* __restrict__ Q,
                                                bf16_t* __restrict__ K,
                                                bf16_t* __restrict__ V) {
  const bf16_t* W = (blockIdx.z == 0) ? Wq : (blockIdx.z == 1) ? Wk : Wv;
  bf16_t* O = (blockIdx.z == 0) ? Q : (blockIdx.z == 1) ? K : V;
  gemm128_body<0>(X, W, O, nullptr, nullptr);
}

__global__ __launch_bounds__(256) void gemm_out(const bf16_t* __restrict__ Attn,
                                                const bf16_t* __restrict__ Wo,
                                                float* __restrict__ Y,
                                                const float* __restrict__ X) {
  gemm128_body<1>(Attn, Wo, nullptr, Y, X);
}

// ---------------- flash attention: 1 wave per (b, h, 16-row q tile) ----------------
__global__ __launch_bounds__(64) void attn_kernel(const bf16_t* __restrict__ Q,
                                                  const bf16_t* __restrict__ K,
                                                  const bf16_t* __restrict__ V,
                                                  bf16_t* __restrict__ Oout) {
  const int lane = threadIdx.x;
  const int q0 = blockIdx.x * 16;
  const int h = blockIdx.y;
  const int b = blockIdx.z;
  const size_t baseRow = (size_t)b * SEQ;
  const int hoff = h * HD;
  const int lr = lane & 15, lg = lane >> 4;

  __shared__ __align__(16) bf16_t Pl[16 * 32];

  // Q fragments for the 16x64 tile (K-dim = d, two k-steps of 32)
  bf16x8 qf[2];
#pragma unroll
  for (int kk = 0; kk < 2; ++kk)
    qf[kk] = *reinterpret_cast<const bf16x8*>(
        &Q[(baseRow + q0 + lr) * EMB + hoff + kk * 32 + lg * 8]);

  f32x4 o[4] = {};
  float mrow[4], lrow[4];
#pragma unroll
  for (int r = 0; r < 4; ++r) { mrow[r] = -1e30f; lrow[r] = 0.f; }
  const float scale = 0.125f;  // 1/sqrt(64)

  for (int j0 = 0; j0 < SEQ; j0 += 32) {
    // scores for 32 kv columns: two 16-wide n-tiles
    f32x4 s[2] = {};
#pragma unroll
    for (int t = 0; t < 2; ++t)
#pragma unroll
      for (int kk = 0; kk < 2; ++kk) {
        bf16x8 kf = *reinterpret_cast<const bf16x8*>(
            &K[(baseRow + j0 + t * 16 + lr) * EMB + hoff + kk * 32 + lg * 8]);
        s[t] = __builtin_amdgcn_mfma_f32_16x16x32_bf16(qf[kk], kf, s[t], 0, 0, 0);
      }
#pragma unroll
    for (int t = 0; t < 2; ++t)
#pragma unroll
      for (int r = 0; r < 4; ++r) s[t][r] *= scale;

    // online softmax; row (lg*4+r) stats reduced across the 16 lanes sharing lg
    float alpha[4];
#pragma unroll
    for (int r = 0; r < 4; ++r) {
      float mv = fmaxf(s[0][r], s[1][r]);
      mv = fmaxf(mv, __shfl_xor(mv, 1));
      mv = fmaxf(mv, __shfl_xor(mv, 2));
      mv = fmaxf(mv, __shfl_xor(mv, 4));
      mv = fmaxf(mv, __shfl_xor(mv, 8));
      float mn = fmaxf(mrow[r], mv);
      alpha[r] = __expf(mrow[r] - mn);
      mrow[r] = mn;
    }
#pragma unroll
    for (int t = 0; t < 2; ++t)
#pragma unroll
      for (int r = 0; r < 4; ++r) s[t][r] = __expf(s[t][r] - mrow[r]);
#pragma unroll
    for (int r = 0; r < 4; ++r) {
      float sv = s[0][r] + s[1][r];
      sv += __shfl_xor(sv, 1);
      sv += __shfl_xor(sv, 2);
      sv += __shfl_xor(sv, 4);
      sv += __shfl_xor(sv, 8);
      lrow[r] = lrow[r] * alpha[r] + sv;
    }
#pragma unroll
    for (int t = 0; t < 4; ++t)
#pragma unroll
      for (int r = 0; r < 4; ++r) o[t][r] *= alpha[r];

    // P (16x32) -> LDS bf16, then re-read as PV A-fragment
    __syncthreads();
#pragma unroll
    for (int t = 0; t < 2; ++t)
#pragma unroll
      for (int r = 0; r < 4; ++r)
        Pl[(lg * 4 + r) * 32 + t * 16 + lr] = __float2bfloat16(s[t][r]);
    __syncthreads();
    bf16x8 pf = *reinterpret_cast<const bf16x8*>(&Pl[lr * 32 + lg * 8]);

    // V B-fragments (strided scalar loads — optimize later), k-dim = 32 kv rows
#pragma unroll
    for (int t = 0; t < 4; ++t) {
      union { bf16x8 v8; bf16_t hx[8]; } vu;
#pragma unroll
      for (int jj = 0; jj < 8; ++jj)
        vu.hx[jj] = V[(baseRow + j0 + lg * 8 + jj) * EMB + hoff + t * 16 + lr];
      o[t] = __builtin_amdgcn_mfma_f32_16x16x32_bf16(pf, vu.v8, o[t], 0, 0, 0);
    }
  }

#pragma unroll
  for (int t = 0; t < 4; ++t)
#pragma unroll
    for (int r = 0; r < 4; ++r) {
      float val = o[t][r] / lrow[r];
      Oout[(baseRow + q0 + lg * 4 + r) * EMB + hoff + t * 16 + lr] = __float2bfloat16(val);
    }
}

// ---------------- row LayerNorm (1024 cols), f32 ----------------
__global__ __launch_bounds__(256) void ln_kernel(const float* __restrict__ Y,
                                                 const float* __restrict__ gamma,
                                                 const float* __restrict__ beta,
                                                 float* __restrict__ Out) {
  const int row = blockIdx.x;
  const int tid = threadIdx.x;
  const float4 v = reinterpret_cast<const float4*>(Y + (size_t)row * EMB)[tid];
  float s = v.x + v.y + v.z + v.w;
  float s2 = v.x * v.x + v.y * v.y + v.z * v.z + v.w * v.w;
#pragma unroll
  for (int m = 1; m < 64; m <<= 1) {
    s += __shfl_xor(s, m);
    s2 += __shfl_xor(s2, m);
  }
  __shared__ float ws[4], ws2[4];
  const int w = tid >> 6;
  if ((tid & 63) == 0) { ws[w] = s; ws2[w] = s2; }
  __syncthreads();
  s = ws[0] + ws[1] + ws[2] + ws[3];
  s2 = ws2[0] + ws2[1] + ws2[2] + ws2[3];
  const float mu = s * (1.f / EMB);
  const float var = s2 * (1.f / EMB) - mu * mu;
  const float rstd = rsqrtf(var + 1e-5f);
  const float4 g = reinterpret_cast<const float4*>(gamma)[tid];
  const float4 bt = reinterpret_cast<const float4*>(beta)[tid];
  float4 ov;
  ov.x = (v.x - mu) * rstd * g.x + bt.x;
  ov.y = (v.y - mu) * rstd * g.y + bt.y;
  ov.z = (v.z - mu) * rstd * g.z + bt.z;
  ov.w = (v.w - mu) * rstd * g.w + bt.w;
  reinterpret_cast<float4*>(Out + (size_t)row * EMB)[tid] = ov;
}

// ---------------- launch ----------------
extern "C" void kernel_launch(void* const* d_in, const int* in_sizes, int n_in,
                              void* d_out, int out_size, void* d_ws, size_t ws_size,
                              hipStream_t stream) {
  const float* x = (const float*)d_in[0];
  const float* Wq = (const float*)d_in[1];
  const float* Wk = (const float*)d_in[2];
  const float* Wv = (const float*)d_in[3];
  const float* Wo = (const float*)d_in[4];
  const float* gamma = (const float*)d_in[5];
  const float* beta = (const float*)d_in[6];
  float* out = (float*)d_out;

  char* p = (char*)d_ws;
  const size_t sz_rows_bf = (size_t)NROWS * EMB * sizeof(bf16_t);  // 8 MB
  const size_t sz_w_bf = (size_t)EMB * EMB * sizeof(bf16_t);       // 2 MB
  bf16_t* xb = (bf16_t*)p; p += sz_rows_bf;
  bf16_t* wqb = (bf16_t*)p; p += sz_w_bf;
  bf16_t* wkb = (bf16_t*)p; p += sz_w_bf;
  bf16_t* wvb = (bf16_t*)p; p += sz_w_bf;
  bf16_t* wob = (bf16_t*)p; p += sz_w_bf;
  bf16_t* q = (bf16_t*)p; p += sz_rows_bf;
  bf16_t* k = (bf16_t*)p; p += sz_rows_bf;
  bf16_t* v = (bf16_t*)p; p += sz_rows_bf;
  bf16_t* attn = (bf16_t*)p; p += sz_rows_bf;
  float* y = (float*)q;  // alias: q/k/v dead after attn_kernel; y (16MB) fits in q+k

  // casts
  const int n4x = NROWS * EMB / 4;
  const int n4w = EMB * EMB / 4;
  cast_f32_to_bf16<<<n4x / 256, 256, 0, stream>>>(x, xb, n4x);
  cast_f32_to_bf16<<<n4w / 256, 256, 0, stream>>>(Wq, wqb, n4w);
  cast_f32_to_bf16<<<n4w / 256, 256, 0, stream>>>(Wk, wkb, n4w);
  cast_f32_to_bf16<<<n4w / 256, 256, 0, stream>>>(Wv, wvb, n4w);
  cast_f32_to_bf16<<<n4w / 256, 256, 0, stream>>>(Wo, wob, n4w);

  // QKV projections (fused z-dim)
  gemm_qkv<<<dim3(EMB / 128, NROWS / 128, 3), 256, 0, stream>>>(xb, wqb, wkb, wvb, q, k, v);

  // attention
  attn_kernel<<<dim3(SEQ / 16, NHEAD, BATCH), 64, 0, stream>>>(q, k, v, attn);

  // out projection + residual
  gemm_out<<<dim3(EMB / 128, NROWS / 128, 1), 256, 0, stream>>>(attn, wob, y, x);

  // layernorm
  ln_kernel<<<NROWS, 256, 0, stream>>>(y, gamma, beta, out);
}

// Round 2
// 150.185 us; speedup vs baseline: 1.7437x; 1.7437x over previous
//
#include <hip/hip_runtime.h>
#include <hip/hip_bf16.h>
#include <cstdint>
#include <cstddef>

#define SEQ   2048
#define BATCH 2
#define NROWS 4096          // BATCH*SEQ
#define EMB   1024
#define NHEAD 16
#define HD    64
#define QBLK  64
#define KVBLK 64

typedef __attribute__((ext_vector_type(8))) short bf16x8;
typedef __attribute__((ext_vector_type(4))) float f32x4;
typedef __hip_bfloat16 bf16_t;

__device__ __forceinline__ int swz(int row, int cb) { return cb ^ ((row & 7) << 4); }

// ---------------- cast f32 -> bf16 (vectorized) ----------------
__global__ __launch_bounds__(256) void cast_f32_to_bf16(const float* __restrict__ in,
                                                        bf16_t* __restrict__ out, int n4) {
  int i = blockIdx.x * 256 + threadIdx.x;
  if (i >= n4) return;
  float4 v = reinterpret_cast<const float4*>(in)[i];
  union { ushort4 u; bf16_t h[4]; } o;
  o.h[0] = __float2bfloat16(v.x);
  o.h[1] = __float2bfloat16(v.y);
  o.h[2] = __float2bfloat16(v.z);
  o.h[3] = __float2bfloat16(v.w);
  reinterpret_cast<ushort4*>(out)[i] = o.u;
}

// ---------------- 128x128 bf16 MFMA GEMM (m97 structure) ----------------
// Y = A @ W^T, A [M][1024] bf16 row-major, W [N][1024] bf16 row-major.
// MODE 0: bf16 row-major out. MODE 1: f32 out = acc + Res. MODE 2: bf16 out
// written head-transposed: Vt[(row>>11)*1024 + col][row&2047].
template <int MODE>
__device__ __forceinline__ void gemm128_body(const bf16_t* __restrict__ A,
                                             const bf16_t* __restrict__ W,
                                             bf16_t* __restrict__ Ob,
                                             float* __restrict__ Of,
                                             const float* __restrict__ Res) {
  __shared__ __align__(16) bf16_t As[128 * 32];
  __shared__ __align__(16) bf16_t Bs[128 * 32];
  const int tid = threadIdx.x;
  const int lane = tid & 63;
  const int wv = tid >> 6;
  const int wm = wv >> 1, wn = wv & 1;          // 2x2 waves, each owns 64x64
  const int brow = blockIdx.y * 128;
  const int bcol = blockIdx.x * 128;
  const int lr = lane & 15, lg = lane >> 4;

  f32x4 acc[4][4] = {};

  auto* As3 = (__attribute__((address_space(3))) char*)As;
  auto* Bs3 = (__attribute__((address_space(3))) char*)Bs;

  for (int k0 = 0; k0 < EMB; k0 += 32) {
    __syncthreads();
#pragma unroll
    for (int i = 0; i < 2; ++i) {
      const int chunk = i * 256 + tid;          // 0..511, 16B each
      const int row = chunk >> 2;               // tile row 0..127
      const int kc = (chunk & 3) * 8;           // k element 0/8/16/24
      const bf16_t* ga = A + (size_t)(brow + row) * EMB + k0 + kc;
      const bf16_t* gb = W + (size_t)(bcol + row) * EMB + k0 + kc;
      __builtin_amdgcn_global_load_lds((const __attribute__((address_space(1))) void*)ga,
                                       (__attribute__((address_space(3))) void*)(As3 + chunk * 16),
                                       16, 0, 0);
      __builtin_amdgcn_global_load_lds((const __attribute__((address_space(1))) void*)gb,
                                       (__attribute__((address_space(3))) void*)(Bs3 + chunk * 16),
                                       16, 0, 0);
    }
    __syncthreads();

    bf16x8 af[4], bfr[4];
#pragma unroll
    for (int m = 0; m < 4; ++m)
      af[m] = *reinterpret_cast<const bf16x8*>(&As[(wm * 64 + m * 16 + lr) * 32 + lg * 8]);
#pragma unroll
    for (int n = 0; n < 4; ++n)
      bfr[n] = *reinterpret_cast<const bf16x8*>(&Bs[(wn * 64 + n * 16 + lr) * 32 + lg * 8]);
#pragma unroll
    for (int m = 0; m < 4; ++m)
#pragma unroll
      for (int n = 0; n < 4; ++n)
        acc[m][n] = __builtin_amdgcn_mfma_f32_16x16x32_bf16(af[m], bfr[n], acc[m][n], 0, 0, 0);
  }

  const int r0 = brow + wm * 64;
  const int c0 = bcol + wn * 64;
#pragma unroll
  for (int m = 0; m < 4; ++m)
#pragma unroll
    for (int n = 0; n < 4; ++n) {
      if (MODE == 2) {
        // pack 4 consecutive rows (r) = 4 consecutive s in Vt
        const int row0 = r0 + m * 16 + lg * 4;
        const int col = c0 + n * 16 + lr;
        const size_t vt_row = (size_t)(row0 >> 11) * 1024 + col;
        const int s = row0 & 2047;
        union { uint2 u2; bf16_t h[4]; } pu;
#pragma unroll
        for (int r = 0; r < 4; ++r) pu.h[r] = __float2bfloat16(acc[m][n][r]);
        *reinterpret_cast<uint2*>(Ob + vt_row * SEQ + s) = pu.u2;
      } else {
#pragma unroll
        for (int r = 0; r < 4; ++r) {
          const int row = r0 + m * 16 + lg * 4 + r;
          const int col = c0 + n * 16 + lr;
          const size_t idx = (size_t)row * EMB + col;
          if (MODE == 0) Ob[idx] = __float2bfloat16(acc[m][n][r]);
          else Of[idx] = acc[m][n][r] + Res[idx];
        }
      }
    }
}

__global__ __launch_bounds__(256) void gemm_qkv(const bf16_t* __restrict__ X,
                                                const bf16_t* __restrict__ Wq,
                                                const bf16_t* __restrict__ Wk,
                                                const bf16_t* __restrict__ Wv,
                                                bf16_t* __restrict__ Q,
                                                bf16_t* __restrict__ K,
                                                bf16_t* __restrict__ Vt) {
  if (blockIdx.z == 0)      gemm128_body<0>(X, Wq, Q, nullptr, nullptr);
  else if (blockIdx.z == 1) gemm128_body<0>(X, Wk, K, nullptr, nullptr);
  else                      gemm128_body<2>(X, Wv, Vt, nullptr, nullptr);
}

__global__ __launch_bounds__(256) void gemm_out(const bf16_t* __restrict__ Attn,
                                                const bf16_t* __restrict__ Wo,
                                                float* __restrict__ Y,
                                                const float* __restrict__ X) {
  gemm128_body<1>(Attn, Wo, nullptr, Y, X);
}

// ---------------- flash attention: 4 waves/block, swapped QK^T, Vt staged ----------------
__global__ __launch_bounds__(256) void attn_kernel(const bf16_t* __restrict__ Q,
                                                   const bf16_t* __restrict__ K,
                                                   const bf16_t* __restrict__ Vt,
                                                   bf16_t* __restrict__ Oout) {
  __shared__ __align__(16) bf16_t Ks[KVBLK * 64];    // swizzled [j][d]
  __shared__ __align__(16) bf16_t Vs[64 * KVBLK];    // swizzled [d][j]
  __shared__ __align__(16) bf16_t Pl[4][16 * 64];    // per-wave P [q][j] swizzled

  const int tid = threadIdx.x;
  const int lane = tid & 63;
  const int wv = tid >> 6;
  const int lr = lane & 15, lg = lane >> 4;

  // XCD-aware bijective swizzle: 1024 blocks -> each XCD gets 4 full (b,h) groups
  const int f = blockIdx.x + 32 * blockIdx.y + 512 * blockIdx.z;
  const int w = (f & 7) * 128 + (f >> 3);
  const int qb = w & 31;
  const int h = (w >> 5) & 15;
  const int b = w >> 9;

  const size_t baseRow = (size_t)b * SEQ;
  const int hoff = h * HD;
  const int q0 = qb * QBLK + wv * 16;

  // Q fragments, pre-scaled by 1/8 (exact in bf16)
  bf16x8 qf[2];
#pragma unroll
  for (int kk = 0; kk < 2; ++kk) {
    bf16x8 t = *reinterpret_cast<const bf16x8*>(
        &Q[(baseRow + q0 + lr) * EMB + hoff + kk * 32 + lg * 8]);
    union { bf16x8 v; bf16_t h[8]; } u;
    u.v = t;
#pragma unroll
    for (int e = 0; e < 8; ++e)
      u.h[e] = __float2bfloat16(__bfloat162float(u.h[e]) * 0.125f);
    qf[kk] = u.v;
  }

  f32x4 o[4] = {};
  float mrow = -1e30f, lrow = 0.f;

  auto* Ks3 = (__attribute__((address_space(3))) char*)Ks;
  auto* Vs3 = (__attribute__((address_space(3))) char*)Vs;

  const bf16_t* Kg = K + baseRow * EMB + hoff;
  const bf16_t* Vg = Vt + (size_t)(b * 1024 + hoff) * SEQ;

  for (int j0 = 0; j0 < SEQ; j0 += KVBLK) {
    __syncthreads();  // previous tile consumed
#pragma unroll
    for (int i = 0; i < 2; ++i) {
      const int c = i * 256 + tid;              // 0..511
      const int row = c >> 3;                   // 0..63
      const int cb = swz(row, (c & 7) * 16);    // swizzled byte-in-row (source side)
      const bf16_t* gk = Kg + (size_t)(j0 + row) * EMB + (cb >> 1);
      const bf16_t* gv = Vg + (size_t)row * SEQ + j0 + (cb >> 1);
      __builtin_amdgcn_global_load_lds((const __attribute__((address_space(1))) void*)gk,
                                       (__attribute__((address_space(3))) void*)(Ks3 + c * 16),
                                       16, 0, 0);
      __builtin_amdgcn_global_load_lds((const __attribute__((address_space(1))) void*)gv,
                                       (__attribute__((address_space(3))) void*)(Vs3 + c * 16),
                                       16, 0, 0);
    }
    __syncthreads();  // staged data visible

    // ---- S^T = K . Q^T : lane holds S^T[j = t*16+lg*4+r][q = lr] ----
    f32x4 st[4] = {};
#pragma unroll
    for (int t = 0; t < 4; ++t) {
      const int row = t * 16 + lr;
#pragma unroll
      for (int kk = 0; kk < 2; ++kk) {
        bf16x8 kf = *reinterpret_cast<const bf16x8*>(
            (const char*)Ks + row * 128 + swz(lr, kk * 64 + lg * 16));
        st[t] = __builtin_amdgcn_mfma_f32_16x16x32_bf16(kf, qf[kk], st[t], 0, 0, 0);
      }
    }

    // ---- online softmax (per-lane row q=lr; reduce across lg via 2 shfls) ----
    float mx = -1e30f;
#pragma unroll
    for (int t = 0; t < 4; ++t)
#pragma unroll
      for (int r = 0; r < 4; ++r) mx = fmaxf(mx, st[t][r]);
    mx = fmaxf(mx, __shfl_xor(mx, 16));
    mx = fmaxf(mx, __shfl_xor(mx, 32));
    const float mnew = fmaxf(mrow, mx);
    const float alpha = __expf(mrow - mnew);
    mrow = mnew;

    float p[16];
    float ls = 0.f;
#pragma unroll
    for (int t = 0; t < 4; ++t)
#pragma unroll
      for (int r = 0; r < 4; ++r) {
        const float pv = __expf(st[t][r] - mnew);
        p[t * 4 + r] = pv;
        ls += pv;
      }
    ls += __shfl_xor(ls, 16);
    ls += __shfl_xor(ls, 32);
    lrow = lrow * alpha + ls;
#pragma unroll
    for (int t = 0; t < 4; ++t)
#pragma unroll
      for (int r = 0; r < 4; ++r) o[t][r] *= alpha;

    // ---- P -> LDS (bf16, packed 4 consecutive j per write) ----
    char* Plw = (char*)&Pl[wv][0];
#pragma unroll
    for (int t = 0; t < 4; ++t) {
      union { uint2 u2; bf16_t h[4]; } pu;
#pragma unroll
      for (int r = 0; r < 4; ++r) pu.h[r] = __float2bfloat16(p[t * 4 + r]);
      *reinterpret_cast<uint2*>(Plw + lr * 128 + swz(lr, t * 32 + lg * 8)) = pu.u2;
    }
    bf16x8 pf[2];
#pragma unroll
    for (int jt = 0; jt < 2; ++jt)
      pf[jt] = *reinterpret_cast<const bf16x8*>(Plw + lr * 128 + swz(lr, jt * 64 + lg * 16));

    // ---- O^T += Vt . P : lane accumulates O^T[d = t*16+lg*4+r][q = lr] ----
#pragma unroll
    for (int t = 0; t < 4; ++t) {
      const int row = t * 16 + lr;
#pragma unroll
      for (int jt = 0; jt < 2; ++jt) {
        bf16x8 vf = *reinterpret_cast<const bf16x8*>(
            (const char*)Vs + row * 128 + swz(lr, jt * 64 + lg * 16));
        o[t] = __builtin_amdgcn_mfma_f32_16x16x32_bf16(vf, pf[jt], o[t], 0, 0, 0);
      }
    }
  }

  // ---- epilogue: lane owns q = lr, d = t*16+lg*4+r (4 consecutive -> uint2) ----
  const float inv = 1.f / lrow;
  const size_t orow = (baseRow + q0 + lr) * EMB + hoff;
#pragma unroll
  for (int t = 0; t < 4; ++t) {
    union { uint2 u2; bf16_t h[4]; } pu;
#pragma unroll
    for (int r = 0; r < 4; ++r) pu.h[r] = __float2bfloat16(o[t][r] * inv);
    *reinterpret_cast<uint2*>(Oout + orow + t * 16 + lg * 4) = pu.u2;
  }
}

// ---------------- row LayerNorm (1024 cols), f32 ----------------
__global__ __launch_bounds__(256) void ln_kernel(const float* __restrict__ Y,
                                                 const float* __restrict__ gamma,
                                                 const float* __restrict__ beta,
                                                 float* __restrict__ Out) {
  const int row = blockIdx.x;
  const int tid = threadIdx.x;
  const float4 v = reinterpret_cast<const float4*>(Y + (size_t)row * EMB)[tid];
  float s = v.x + v.y + v.z + v.w;
  float s2 = v.x * v.x + v.y * v.y + v.z * v.z + v.w * v.w;
#pragma unroll
  for (int m = 1; m < 64; m <<= 1) {
    s += __shfl_xor(s, m);
    s2 += __shfl_xor(s2, m);
  }
  __shared__ float ws[4], ws2[4];
  const int w = tid >> 6;
  if ((tid & 63) == 0) { ws[w] = s; ws2[w] = s2; }
  __syncthreads();
  s = ws[0] + ws[1] + ws[2] + ws[3];
  s2 = ws2[0] + ws2[1] + ws2[2] + ws2[3];
  const float mu = s * (1.f / EMB);
  const float var = s2 * (1.f / EMB) - mu * mu;
  const float rstd = rsqrtf(var + 1e-5f);
  const float4 g = reinterpret_cast<const float4*>(gamma)[tid];
  const float4 bt = reinterpret_cast<const float4*>(beta)[tid];
  float4 ov;
  ov.x = (v.x - mu) * rstd * g.x + bt.x;
  ov.y = (v.y - mu) * rstd * g.y + bt.y;
  ov.z = (v.z - mu) * rstd * g.z + bt.z;
  ov.w = (v.w - mu) * rstd * g.w + bt.w;
  reinterpret_cast<float4*>(Out + (size_t)row * EMB)[tid] = ov;
}

// ---------------- launch ----------------
extern "C" void kernel_launch(void* const* d_in, const int* in_sizes, int n_in,
                              void* d_out, int out_size, void* d_ws, size_t ws_size,
                              hipStream_t stream) {
  const float* x = (const float*)d_in[0];
  const float* Wq = (const float*)d_in[1];
  const float* Wk = (const float*)d_in[2];
  const float* Wv = (const float*)d_in[3];
  const float* Wo = (const float*)d_in[4];
  const float* gamma = (const float*)d_in[5];
  const float* beta = (const float*)d_in[6];
  float* out = (float*)d_out;

  char* p = (char*)d_ws;
  const size_t sz_rows_bf = (size_t)NROWS * EMB * sizeof(bf16_t);  // 8 MB
  const size_t sz_w_bf = (size_t)EMB * EMB * sizeof(bf16_t);       // 2 MB
  bf16_t* xb = (bf16_t*)p; p += sz_rows_bf;
  bf16_t* wqb = (bf16_t*)p; p += sz_w_bf;
  bf16_t* wkb = (bf16_t*)p; p += sz_w_bf;
  bf16_t* wvb = (bf16_t*)p; p += sz_w_bf;
  bf16_t* wob = (bf16_t*)p; p += sz_w_bf;
  bf16_t* q = (bf16_t*)p; p += sz_rows_bf;
  bf16_t* k = (bf16_t*)p; p += sz_rows_bf;
  bf16_t* vt = (bf16_t*)p; p += sz_rows_bf;   // [B*H*D][S] = 2048 x 2048
  bf16_t* attn = (bf16_t*)p; p += sz_rows_bf;
  float* y = (float*)q;  // alias: q/k dead after attn_kernel; y (16MB) = q+k

  const int n4x = NROWS * EMB / 4;
  const int n4w = EMB * EMB / 4;
  cast_f32_to_bf16<<<n4x / 256, 256, 0, stream>>>(x, xb, n4x);
  cast_f32_to_bf16<<<n4w / 256, 256, 0, stream>>>(Wq, wqb, n4w);
  cast_f32_to_bf16<<<n4w / 256, 256, 0, stream>>>(Wk, wkb, n4w);
  cast_f32_to_bf16<<<n4w / 256, 256, 0, stream>>>(Wv, wvb, n4w);
  cast_f32_to_bf16<<<n4w / 256, 256, 0, stream>>>(Wo, wob, n4w);

  gemm_qkv<<<dim3(EMB / 128, NROWS / 128, 3), 256, 0, stream>>>(xb, wqb, wkb, wvb, q, k, vt);

  attn_kernel<<<dim3(SEQ / QBLK, NHEAD, BATCH), 256, 0, stream>>>(q, k, vt, attn);

  gemm_out<<<dim3(EMB / 128, NROWS / 128, 1), 256, 0, stream>>>(attn, wob, y, x);

  ln_kernel<<<NROWS, 256, 0, stream>>>(y, gamma, beta, out);
}

// Round 3
// 140.002 us; speedup vs baseline: 1.8706x; 1.0727x over previous
//
#include <hip/hip_runtime.h>
#include <hip/hip_bf16.h>
#include <cstdint>
#include <cstddef>

#define SEQ   2048
#define BATCH 2
#define NROWS 4096          // BATCH*SEQ
#define EMB   1024
#define NHEAD 16
#define HD    64
#define QBLK  64
#define KVBLK 64

typedef __attribute__((ext_vector_type(8))) short bf16x8;
typedef __attribute__((ext_vector_type(4))) float f32x4;
typedef __hip_bfloat16 bf16_t;

__device__ __forceinline__ int swz(int row, int cb) { return cb ^ ((row & 7) << 4); }

// ---------------- casts f32 -> bf16 (vectorized) ----------------
__global__ __launch_bounds__(256) void cast_f32_to_bf16(const float* __restrict__ in,
                                                        bf16_t* __restrict__ out, int n4) {
  int i = blockIdx.x * 256 + threadIdx.x;
  if (i >= n4) return;
  float4 v = reinterpret_cast<const float4*>(in)[i];
  union { ushort4 u; bf16_t h[4]; } o;
  o.h[0] = __float2bfloat16(v.x);
  o.h[1] = __float2bfloat16(v.y);
  o.h[2] = __float2bfloat16(v.z);
  o.h[3] = __float2bfloat16(v.w);
  reinterpret_cast<ushort4*>(out)[i] = o.u;
}

// 4 weight matrices in one launch (z selects)
__global__ __launch_bounds__(256) void cast4_w(const float* __restrict__ a,
                                               const float* __restrict__ b,
                                               const float* __restrict__ c,
                                               const float* __restrict__ d,
                                               bf16_t* __restrict__ oa, bf16_t* __restrict__ ob,
                                               bf16_t* __restrict__ oc, bf16_t* __restrict__ od,
                                               int n4) {
  const int z = blockIdx.z;
  const float* in = (z == 0) ? a : (z == 1) ? b : (z == 2) ? c : d;
  bf16_t* out = (z == 0) ? oa : (z == 1) ? ob : (z == 2) ? oc : od;
  int i = blockIdx.x * 256 + threadIdx.x;
  if (i >= n4) return;
  float4 v = reinterpret_cast<const float4*>(in)[i];
  union { ushort4 u; bf16_t h[4]; } o;
  o.h[0] = __float2bfloat16(v.x);
  o.h[1] = __float2bfloat16(v.y);
  o.h[2] = __float2bfloat16(v.z);
  o.h[3] = __float2bfloat16(v.w);
  reinterpret_cast<ushort4*>(out)[i] = o.u;
}

// ---------------- 128x128 bf16 MFMA GEMM (m97 structure) ----------------
// Y = A @ W^T, A [M][1024] bf16 row-major, W [N][1024] bf16 row-major.
// MODE 0: bf16 row-major out. MODE 1: f32 out = acc + Res. MODE 2: bf16 out
// written head-transposed: Vt[(row>>11)*1024 + col][row&2047].
template <int MODE>
__device__ __forceinline__ void gemm128_body(const bf16_t* __restrict__ A,
                                             const bf16_t* __restrict__ W,
                                             bf16_t* __restrict__ Ob,
                                             float* __restrict__ Of,
                                             const float* __restrict__ Res) {
  __shared__ __align__(16) bf16_t As[128 * 32];
  __shared__ __align__(16) bf16_t Bs[128 * 32];
  const int tid = threadIdx.x;
  const int lane = tid & 63;
  const int wv = tid >> 6;
  const int wm = wv >> 1, wn = wv & 1;          // 2x2 waves, each owns 64x64
  const int brow = blockIdx.y * 128;
  const int bcol = blockIdx.x * 128;
  const int lr = lane & 15, lg = lane >> 4;

  f32x4 acc[4][4] = {};

  auto* As3 = (__attribute__((address_space(3))) char*)As;
  auto* Bs3 = (__attribute__((address_space(3))) char*)Bs;

  for (int k0 = 0; k0 < EMB; k0 += 32) {
    __syncthreads();
#pragma unroll
    for (int i = 0; i < 2; ++i) {
      const int chunk = i * 256 + tid;          // 0..511, 16B each
      const int row = chunk >> 2;               // tile row 0..127
      const int kc = (chunk & 3) * 8;           // k element 0/8/16/24
      const bf16_t* ga = A + (size_t)(brow + row) * EMB + k0 + kc;
      const bf16_t* gb = W + (size_t)(bcol + row) * EMB + k0 + kc;
      __builtin_amdgcn_global_load_lds((const __attribute__((address_space(1))) void*)ga,
                                       (__attribute__((address_space(3))) void*)(As3 + chunk * 16),
                                       16, 0, 0);
      __builtin_amdgcn_global_load_lds((const __attribute__((address_space(1))) void*)gb,
                                       (__attribute__((address_space(3))) void*)(Bs3 + chunk * 16),
                                       16, 0, 0);
    }
    __syncthreads();

    bf16x8 af[4], bfr[4];
#pragma unroll
    for (int m = 0; m < 4; ++m)
      af[m] = *reinterpret_cast<const bf16x8*>(&As[(wm * 64 + m * 16 + lr) * 32 + lg * 8]);
#pragma unroll
    for (int n = 0; n < 4; ++n)
      bfr[n] = *reinterpret_cast<const bf16x8*>(&Bs[(wn * 64 + n * 16 + lr) * 32 + lg * 8]);
#pragma unroll
    for (int m = 0; m < 4; ++m)
#pragma unroll
      for (int n = 0; n < 4; ++n)
        acc[m][n] = __builtin_amdgcn_mfma_f32_16x16x32_bf16(af[m], bfr[n], acc[m][n], 0, 0, 0);
  }

  const int r0 = brow + wm * 64;
  const int c0 = bcol + wn * 64;
#pragma unroll
  for (int m = 0; m < 4; ++m)
#pragma unroll
    for (int n = 0; n < 4; ++n) {
      if (MODE == 2) {
        const int row0 = r0 + m * 16 + lg * 4;
        const int col = c0 + n * 16 + lr;
        const size_t vt_row = (size_t)(row0 >> 11) * 1024 + col;
        const int s = row0 & 2047;
        union { uint2 u2; bf16_t h[4]; } pu;
#pragma unroll
        for (int r = 0; r < 4; ++r) pu.h[r] = __float2bfloat16(acc[m][n][r]);
        *reinterpret_cast<uint2*>(Ob + vt_row * SEQ + s) = pu.u2;
      } else {
#pragma unroll
        for (int r = 0; r < 4; ++r) {
          const int row = r0 + m * 16 + lg * 4 + r;
          const int col = c0 + n * 16 + lr;
          const size_t idx = (size_t)row * EMB + col;
          if (MODE == 0) Ob[idx] = __float2bfloat16(acc[m][n][r]);
          else Of[idx] = acc[m][n][r] + Res[idx];
        }
      }
    }
}

__global__ __launch_bounds__(256) void gemm_qkv(const bf16_t* __restrict__ X,
                                                const bf16_t* __restrict__ Wq,
                                                const bf16_t* __restrict__ Wk,
                                                const bf16_t* __restrict__ Wv,
                                                bf16_t* __restrict__ Q,
                                                bf16_t* __restrict__ K,
                                                bf16_t* __restrict__ Vt) {
  if (blockIdx.z == 0)      gemm128_body<0>(X, Wq, Q, nullptr, nullptr);
  else if (blockIdx.z == 1) gemm128_body<0>(X, Wk, K, nullptr, nullptr);
  else                      gemm128_body<2>(X, Wv, Vt, nullptr, nullptr);
}

__global__ __launch_bounds__(256) void gemm_out(const bf16_t* __restrict__ Attn,
                                                const bf16_t* __restrict__ Wo,
                                                float* __restrict__ Y,
                                                const float* __restrict__ X) {
  gemm128_body<1>(Attn, Wo, nullptr, Y, X);
}

// ---------------- flash attention: 4 waves/block, swapped QK^T, exp2-domain ----------------
// K/V double-buffered (T14 async-STAGE); defer-max (T13); setprio (T5).
__global__ __launch_bounds__(256) void attn_kernel(const bf16_t* __restrict__ Q,
                                                   const bf16_t* __restrict__ K,
                                                   const bf16_t* __restrict__ Vt,
                                                   bf16_t* __restrict__ Oout) {
  __shared__ __align__(16) bf16_t Ks[2][KVBLK * 64];   // swizzled [j][d], 8KB each
  __shared__ __align__(16) bf16_t Vs[2][64 * KVBLK];   // swizzled [d][j], 8KB each
  __shared__ __align__(16) bf16_t Pl[4][16 * 64];      // per-wave P [q][j] swizzled

  const int tid = threadIdx.x;
  const int lane = tid & 63;
  const int wv = tid >> 6;
  const int lr = lane & 15, lg = lane >> 4;

  // XCD-aware bijective swizzle: 1024 blocks -> each XCD gets contiguous (b,h) groups
  const int f = blockIdx.x + 32 * blockIdx.y + 512 * blockIdx.z;
  const int w = (f & 7) * 128 + (f >> 3);
  const int qb = w & 31;
  const int h = (w >> 5) & 15;
  const int b = w >> 9;

  const size_t baseRow = (size_t)b * SEQ;
  const int hoff = h * HD;
  const int q0 = qb * QBLK + wv * 16;

  // Q fragments, pre-scaled by 0.125*log2(e) -> softmax in exp2 domain
  const float qscale = 0.125f * 1.44269504f;
  bf16x8 qf[2];
#pragma unroll
  for (int kk = 0; kk < 2; ++kk) {
    bf16x8 t = *reinterpret_cast<const bf16x8*>(
        &Q[(baseRow + q0 + lr) * EMB + hoff + kk * 32 + lg * 8]);
    union { bf16x8 v; bf16_t h[8]; } u;
    u.v = t;
#pragma unroll
    for (int e = 0; e < 8; ++e)
      u.h[e] = __float2bfloat16(__bfloat162float(u.h[e]) * qscale);
    qf[kk] = u.v;
  }

  f32x4 o[4] = {};
  float mrow = -1e30f, lrow = 0.f;

  auto* Ks3 = (__attribute__((address_space(3))) char*)&Ks[0][0];
  auto* Vs3 = (__attribute__((address_space(3))) char*)&Vs[0][0];

  const bf16_t* Kg = K + baseRow * EMB + hoff;
  const bf16_t* Vg = Vt + (size_t)(b * 1024 + hoff) * SEQ;

  auto stage = [&](int buf, int j0) {
#pragma unroll
    for (int i = 0; i < 2; ++i) {
      const int c = i * 256 + tid;              // 0..511
      const int row = c >> 3;                   // 0..63
      const int cb = swz(row, (c & 7) * 16);    // swizzled byte-in-row (source side)
      const bf16_t* gk = Kg + (size_t)(j0 + row) * EMB + (cb >> 1);
      const bf16_t* gv = Vg + (size_t)row * SEQ + j0 + (cb >> 1);
      __builtin_amdgcn_global_load_lds((const __attribute__((address_space(1))) void*)gk,
                                       (__attribute__((address_space(3))) void*)(Ks3 + buf * 8192 + c * 16),
                                       16, 0, 0);
      __builtin_amdgcn_global_load_lds((const __attribute__((address_space(1))) void*)gv,
                                       (__attribute__((address_space(3))) void*)(Vs3 + buf * 8192 + c * 16),
                                       16, 0, 0);
    }
  };

  stage(0, 0);
  __syncthreads();  // implicit vmcnt(0) drain -> buf0 ready

  for (int it = 0; it < SEQ / KVBLK; ++it) {
    const int cur = it & 1;
    if (it + 1 < SEQ / KVBLK) stage(cur ^ 1, (it + 1) * KVBLK);  // async prefetch

    const char* Kb = (const char*)Ks + cur * 8192;
    const char* Vb = (const char*)Vs + cur * 8192;

    // ---- S^T = K . Q^T : lane holds S^T[j = t*16+lg*4+r][q = lr] (log2 units) ----
    f32x4 st[4] = {};
    __builtin_amdgcn_s_setprio(1);
#pragma unroll
    for (int t = 0; t < 4; ++t) {
      const int row = t * 16 + lr;
#pragma unroll
      for (int kk = 0; kk < 2; ++kk) {
        bf16x8 kf = *reinterpret_cast<const bf16x8*>(Kb + row * 128 + swz(lr, kk * 64 + lg * 16));
        st[t] = __builtin_amdgcn_mfma_f32_16x16x32_bf16(kf, qf[kk], st[t], 0, 0, 0);
      }
    }
    __builtin_amdgcn_s_setprio(0);

    // ---- online softmax, exp2 domain; row stats across lg via 2 shfls ----
    float mx = -1e30f;
#pragma unroll
    for (int t = 0; t < 4; ++t)
#pragma unroll
      for (int r = 0; r < 4; ++r) mx = fmaxf(mx, st[t][r]);
    mx = fmaxf(mx, __shfl_xor(mx, 16));
    mx = fmaxf(mx, __shfl_xor(mx, 32));

    // defer-max: only rescale when the tile max grew by > 8 (p bounded by 2^8)
    if (!__all(mx - mrow <= 8.f)) {
      const float mnew = fmaxf(mrow, mx);
      const float al = __builtin_amdgcn_exp2f(mrow - mnew);
      mrow = mnew;
      lrow *= al;
#pragma unroll
      for (int t = 0; t < 4; ++t)
#pragma unroll
        for (int r = 0; r < 4; ++r) o[t][r] *= al;
    }

    float p[16];
    float ls = 0.f;
#pragma unroll
    for (int t = 0; t < 4; ++t)
#pragma unroll
      for (int r = 0; r < 4; ++r) {
        const float pv = __builtin_amdgcn_exp2f(st[t][r] - mrow);
        p[t * 4 + r] = pv;
        ls += pv;
      }
    ls += __shfl_xor(ls, 16);
    ls += __shfl_xor(ls, 32);
    lrow += ls;

    // ---- P -> LDS (bf16, packed 4 consecutive j per write) ----
    char* Plw = (char*)&Pl[wv][0];
#pragma unroll
    for (int t = 0; t < 4; ++t) {
      union { uint2 u2; bf16_t h[4]; } pu;
#pragma unroll
      for (int r = 0; r < 4; ++r) pu.h[r] = __float2bfloat16(p[t * 4 + r]);
      *reinterpret_cast<uint2*>(Plw + lr * 128 + swz(lr, t * 32 + lg * 8)) = pu.u2;
    }
    bf16x8 pf[2];
#pragma unroll
    for (int jt = 0; jt < 2; ++jt)
      pf[jt] = *reinterpret_cast<const bf16x8*>(Plw + lr * 128 + swz(lr, jt * 64 + lg * 16));

    // ---- O^T += Vt . P : lane accumulates O^T[d = t*16+lg*4+r][q = lr] ----
    __builtin_amdgcn_s_setprio(1);
#pragma unroll
    for (int t = 0; t < 4; ++t) {
      const int row = t * 16 + lr;
#pragma unroll
      for (int jt = 0; jt < 2; ++jt) {
        bf16x8 vf = *reinterpret_cast<const bf16x8*>(Vb + row * 128 + swz(lr, jt * 64 + lg * 16));
        o[t] = __builtin_amdgcn_mfma_f32_16x16x32_bf16(vf, pf[jt], o[t], 0, 0, 0);
      }
    }
    __builtin_amdgcn_s_setprio(0);

    __syncthreads();  // one barrier/tile: prefetched loads drained + buffers consumed
  }

  // ---- epilogue: lane owns q = lr, d = t*16+lg*4+r (4 consecutive -> uint2) ----
  const float inv = 1.f / lrow;
  const size_t orow = (baseRow + q0 + lr) * EMB + hoff;
#pragma unroll
  for (int t = 0; t < 4; ++t) {
    union { uint2 u2; bf16_t h[4]; } pu;
#pragma unroll
    for (int r = 0; r < 4; ++r) pu.h[r] = __float2bfloat16(o[t][r] * inv);
    *reinterpret_cast<uint2*>(Oout + orow + t * 16 + lg * 4) = pu.u2;
  }
}

// ---------------- row LayerNorm (1024 cols), f32 ----------------
__global__ __launch_bounds__(256) void ln_kernel(const float* __restrict__ Y,
                                                 const float* __restrict__ gamma,
                                                 const float* __restrict__ beta,
                                                 float* __restrict__ Out) {
  const int row = blockIdx.x;
  const int tid = threadIdx.x;
  const float4 v = reinterpret_cast<const float4*>(Y + (size_t)row * EMB)[tid];
  float s = v.x + v.y + v.z + v.w;
  float s2 = v.x * v.x + v.y * v.y + v.z * v.z + v.w * v.w;
#pragma unroll
  for (int m = 1; m < 64; m <<= 1) {
    s += __shfl_xor(s, m);
    s2 += __shfl_xor(s2, m);
  }
  __shared__ float ws[4], ws2[4];
  const int w = tid >> 6;
  if ((tid & 63) == 0) { ws[w] = s; ws2[w] = s2; }
  __syncthreads();
  s = ws[0] + ws[1] + ws[2] + ws[3];
  s2 = ws2[0] + ws2[1] + ws2[2] + ws2[3];
  const float mu = s * (1.f / EMB);
  const float var = s2 * (1.f / EMB) - mu * mu;
  const float rstd = rsqrtf(var + 1e-5f);
  const float4 g = reinterpret_cast<const float4*>(gamma)[tid];
  const float4 bt = reinterpret_cast<const float4*>(beta)[tid];
  float4 ov;
  ov.x = (v.x - mu) * rstd * g.x + bt.x;
  ov.y = (v.y - mu) * rstd * g.y + bt.y;
  ov.z = (v.z - mu) * rstd * g.z + bt.z;
  ov.w = (v.w - mu) * rstd * g.w + bt.w;
  reinterpret_cast<float4*>(Out + (size_t)row * EMB)[tid] = ov;
}

// ---------------- launch ----------------
extern "C" void kernel_launch(void* const* d_in, const int* in_sizes, int n_in,
                              void* d_out, int out_size, void* d_ws, size_t ws_size,
                              hipStream_t stream) {
  const float* x = (const float*)d_in[0];
  const float* Wq = (const float*)d_in[1];
  const float* Wk = (const float*)d_in[2];
  const float* Wv = (const float*)d_in[3];
  const float* Wo = (const float*)d_in[4];
  const float* gamma = (const float*)d_in[5];
  const float* beta = (const float*)d_in[6];
  float* out = (float*)d_out;

  char* p = (char*)d_ws;
  const size_t sz_rows_bf = (size_t)NROWS * EMB * sizeof(bf16_t);  // 8 MB
  const size_t sz_w_bf = (size_t)EMB * EMB * sizeof(bf16_t);       // 2 MB
  bf16_t* xb = (bf16_t*)p; p += sz_rows_bf;
  bf16_t* wqb = (bf16_t*)p; p += sz_w_bf;
  bf16_t* wkb = (bf16_t*)p; p += sz_w_bf;
  bf16_t* wvb = (bf16_t*)p; p += sz_w_bf;
  bf16_t* wob = (bf16_t*)p; p += sz_w_bf;
  bf16_t* q = (bf16_t*)p; p += sz_rows_bf;
  bf16_t* k = (bf16_t*)p; p += sz_rows_bf;
  bf16_t* vt = (bf16_t*)p; p += sz_rows_bf;   // [B*H*D][S] = 2048 x 2048
  bf16_t* attn = (bf16_t*)p; p += sz_rows_bf;
  float* y = (float*)q;  // alias: q/k dead after attn_kernel; y (16MB) = q+k

  const int n4x = NROWS * EMB / 4;
  const int n4w = EMB * EMB / 4;
  cast_f32_to_bf16<<<n4x / 256, 256, 0, stream>>>(x, xb, n4x);
  cast4_w<<<dim3(n4w / 256, 1, 4), 256, 0, stream>>>(Wq, Wk, Wv, Wo, wqb, wkb, wvb, wob, n4w);

  gemm_qkv<<<dim3(EMB / 128, NROWS / 128, 3), 256, 0, stream>>>(xb, wqb, wkb, wvb, q, k, vt);

  attn_kernel<<<dim3(SEQ / QBLK, NHEAD, BATCH), 256, 0, stream>>>(q, k, vt, attn);

  gemm_out<<<dim3(EMB / 128, NROWS / 128, 1), 256, 0, stream>>>(attn, wob, y, x);

  ln_kernel<<<NROWS, 256, 0, stream>>>(y, gamma, beta, out);
}